// Round 11
// baseline (341.683 us; speedup 1.0000x reference)
//
#include <hip/hip_runtime.h>
#include <hip/hip_bf16.h>

#define NEG_SLOPE 0.2f
#define HPAD 264   // 256 + 8 ushort pad: breaks pow-2 LDS bank stride

typedef short short8 __attribute__((ext_vector_type(8)));
typedef float floatx4 __attribute__((ext_vector_type(4)));
typedef unsigned short ushort8v __attribute__((ext_vector_type(8)));
typedef unsigned short ushort4v __attribute__((ext_vector_type(4)));
typedef unsigned int uint4v __attribute__((ext_vector_type(4)));

__device__ __forceinline__ float bf2f_raw(unsigned short u) {
    union { float f; unsigned u; } c; c.u = ((unsigned)u) << 16; return c.f;
}
__device__ __forceinline__ float asf(unsigned u) {
    union { float f; unsigned u; } c; c.u = u; return c.f;
}
__device__ __forceinline__ unsigned short f2bf_raw(float f) {
    union { float f; unsigned u; } c; c.f = f;
    unsigned u = c.u;
    u += 0x7FFFu + ((u >> 16) & 1u);   // round-to-nearest-even
    return (unsigned short)(u >> 16);
}
__device__ __forceinline__ float ldf(const void* p, size_t i, int f32) {
    return f32 ? ((const float*)p)[i] : bf2f_raw(((const unsigned short*)p)[i]);
}
__device__ __forceinline__ unsigned short ldbf(const void* p, size_t i, int f32) {
    return f32 ? f2bf_raw(((const float*)p)[i]) : ((const unsigned short*)p)[i];
}
__device__ __forceinline__ int clampN(long long v, int N) {
    if (v < 0) v = 0;
    if (v >= N) v = N - 1;
    return (int)v;
}
__device__ __forceinline__ float lrelu(float v) { return v > 0.f ? v : NEG_SLOPE * v; }

// K0: prep = dtype detect + W transpose + workspace zeroing, ONE kernel
// (round-9 merge, proven clean). Redundant per-block W-dtype detection (8KB
// re-read, L2-served; no cross-block sync). Block 0 writes flags[0..3].
__global__ __launch_bounds__(256) void prep_kernel(
    const void* __restrict__ W, unsigned short* __restrict__ Wt,
    const unsigned short* __restrict__ x,
    const unsigned short* __restrict__ as_, const unsigned short* __restrict__ ad_,
    const unsigned* __restrict__ edge_w, int* __restrict__ flags, int edge_words,
    int* __restrict__ deg8, int* __restrict__ bsync, int N8)
{
    __shared__ float sm[256];
    __shared__ unsigned su[256];
    const int t = threadIdx.x;
    const int i = blockIdx.x * 256 + t;   // 65536 total

    // zero deg8 (8N ints) + bsync
    #pragma unroll
    for (int j = 0; j < 7; ++j) {          // 458752 >= 8*N = 400000
        int z = i + j * 65536;
        if (z < N8) deg8[z] = 0;
    }
    if (i < 256) bsync[i] = 0;

    // every block: detect W dtype locally (bf16-interpreted absmax > 100 -> f32)
    float mw = 0.f;
    for (int k = t; k < 4096; k += 256) {
        float v = fabsf(bf2f_raw(((const unsigned short*)W)[k]));
        mw = fmaxf(mw, (v == v && v < 3e38f) ? v : 1e9f);
    }
    sm[t] = mw; __syncthreads();
    for (int s = 128; s; s >>= 1) { if (t < s) sm[t] = fmaxf(sm[t], sm[t + s]); __syncthreads(); }
    const int wf32 = sm[0] > 100.f;
    __syncthreads();   // protect sm[0] before block-0 reuses sm

    // block 0: full flags for downstream kernels
    if (blockIdx.x == 0) {
        float mx = 0.f, ma = 0.f;
        for (int k = t; k < 4096; k += 256) {
            float v = fabsf(bf2f_raw(x[k]));
            mx = fmaxf(mx, (v == v && v < 3e38f) ? v : 1e9f);
        }
        {
            float v1 = fabsf(bf2f_raw(as_[t]));
            float v2 = fabsf(bf2f_raw(ad_[t]));
            v1 = (v1 == v1 && v1 < 3e38f) ? v1 : 1e9f;
            v2 = (v2 == v2 && v2 < 3e38f) ? v2 : 1e9f;
            ma = fmaxf(v1, v2);
        }
        unsigned ow = 0;
        {
            int k = 2 * t + 1;
            if (k < edge_words) ow = edge_w[k];
        }
        sm[t] = mx; __syncthreads();
        for (int s = 128; s; s >>= 1) { if (t < s) sm[t] = fmaxf(sm[t], sm[t + s]); __syncthreads(); }
        if (t == 0) flags[0] = sm[0] > 100.f;
        __syncthreads();
        sm[t] = ma; __syncthreads();
        for (int s = 128; s; s >>= 1) { if (t < s) sm[t] = fmaxf(sm[t], sm[t + s]); __syncthreads(); }
        if (t == 0) flags[2] = sm[0] > 100.f;
        __syncthreads();
        su[t] = ow; __syncthreads();
        for (int s = 128; s; s >>= 1) { if (t < s) su[t] |= su[t + s]; __syncthreads(); }
        if (t == 0) { flags[3] = (su[0] == 0u); flags[1] = wf32; }
    }

    // W transpose into MFMA B-fragment order, using local wf32
    int j = i & 7;
    int l = (i >> 3) & 63;
    int ks = (i >> 9) & 7;
    int c = i >> 12;
    int k = ks * 32 + (l >> 4) * 8 + j;
    int n = c * 16 + (l & 15);
    Wt[i] = ldbf(W, (size_t)k * 256 + n, wf32);
}

// K1: MFMA gemm INTERLEAVED with count (proven round 8: Bresenham role-spread).
// v11: h output written in SLAB layout h[s][n][32cols] (8 slabs of 3.2MB) so
// the aggregate can keep each slab resident in ONE XCD's 4MB L2 (round 7-10
// evidence: aggregate's random 512B gathers from the 25.6MB row-major table
// are fabric-limited at ~2.9 MB/us regardless of implementation).
// Store remap keeps full-line coalescing: threads t..t+127 write 2KB
// contiguous within one slab (chunk c: slab=c>>7, row=(c&127)>>2, c4=c&3).
__global__ __launch_bounds__(512) void gemm_count_kernel(
    const void* __restrict__ x, const unsigned short* __restrict__ Wt,
    const void* __restrict__ att_src, const void* __restrict__ att_dst,
    unsigned short* __restrict__ h_out, float* __restrict__ a_s, float* __restrict__ a_d,
    const void* __restrict__ edge, int* __restrict__ deg8, int* __restrict__ rank,
    const int* __restrict__ flags, int N, int E, int ntiles,
    int ngemm, int ncount, int ntotal)
{
    const unsigned long long bi = blockIdx.x;
    const unsigned before = (unsigned)((bi * (unsigned long long)ncount) / ntotal);
    const unsigned after  = (unsigned)(((bi + 1) * (unsigned long long)ncount) / ntotal);

    if (after != before) {
        // ---- count role: block index cb = before ----
        const int cb = (int)before;
        const int base = cb * 2048 + threadIdx.x * 4;
        if (base >= E) return;
        int* my = deg8 + (size_t)(cb & 7) * N;
        const int cnt = (E - base < 4) ? (E - base) : 4;
        int d[4];
        if (flags[3]) {
            const long long* p = (const long long*)edge + E + base;
            #pragma unroll
            for (int k = 0; k < 4; ++k) d[k] = clampN((k < cnt) ? p[k] : 0, N);
        } else {
            const int* p = (const int*)edge + E + base;
            #pragma unroll
            for (int k = 0; k < 4; ++k) d[k] = clampN((k < cnt) ? (long long)p[k] : 0, N);
        }
        int r[4] = {0, 0, 0, 0};
        #pragma unroll
        for (int k = 0; k < 4; ++k)
            if (k < cnt) r[k] = atomicAdd(&my[d[k]], 1);
        #pragma unroll
        for (int k = 0; k < 4; ++k)
            if (k < cnt) rank[base + k] = r[k];
        return;
    }

    // ---- gemm role: block index gb = bi - before ----
    const int gb = (int)(bi - before);

    __shared__ unsigned short sh_h[32][HPAD];   // 32-row tile, all 256 cols
    __shared__ float sh_a[2][32][4];            // [as/ad][row][head]

    const int w = threadIdx.x >> 6;             // wave 0..7
    const int head = w >> 1;
    const int st = w & 1;                       // row-subtile 0/1
    const int l = threadIdx.x & 63;
    const int lane16 = l & 15;
    const int quad = l >> 4;
    const int xf = flags[0], af = flags[2];
    const int n0w = head * 64;
    const size_t slabN = (size_t)N * 32;

    float as_att[4], ad_att[4];
    #pragma unroll
    for (int nt = 0; nt < 4; ++nt) {
        as_att[nt] = ldf(att_src, n0w + nt * 16 + lane16, af);
        ad_att[nt] = ldf(att_dst, n0w + nt * 16 + lane16, af);
    }

    for (int tile = gb; tile < ntiles; tile += ngemm) {
        const int m0 = tile * 32;
        int r0 = m0 + st * 16 + lane16;
        if (r0 >= N) r0 = N - 1;

        floatx4 acc[4];
        #pragma unroll
        for (int nt = 0; nt < 4; ++nt) acc[nt] = (floatx4){0.f, 0.f, 0.f, 0.f};

        const unsigned short* wp0 = Wt + (((size_t)head * 32) * 64 + l) * 8;

        #pragma unroll
        for (int half = 0; half < 2; ++half) {
            short8 fa[4];
            if (!xf) {
                const char* b0 = (const char*)x + ((size_t)r0 * 256 + quad * 8) * 2 + half * 256;
                #pragma unroll
                for (int k4 = 0; k4 < 4; ++k4)
                    fa[k4] = *(const short8*)(b0 + k4 * 64);
            } else {
                const float* b0 = (const float*)x + (size_t)r0 * 256 + quad * 8 + half * 128;
                #pragma unroll
                for (int k4 = 0; k4 < 4; ++k4) {
                    #pragma unroll
                    for (int j = 0; j < 8; ++j)
                        fa[k4][j] = (short)f2bf_raw(b0[k4 * 32 + j]);
                }
            }

            #pragma unroll
            for (int k4 = 0; k4 < 4; ++k4) {
                const unsigned short* wp = wp0 + (size_t)(half * 4 + k4) * 512;
                #pragma unroll
                for (int nt = 0; nt < 4; ++nt) {
                    short8 fb = *(const short8*)(wp + nt * 4096);
                    acc[nt] = __builtin_amdgcn_mfma_f32_16x16x32_bf16(fa[k4], fb, acc[nt], 0, 0, 0);
                }
            }
        }

        __syncthreads();   // WAR: previous iteration's LDS fully consumed

        #pragma unroll
        for (int nt = 0; nt < 4; ++nt) {
            #pragma unroll
            for (int r = 0; r < 4; ++r) {
                sh_h[st * 16 + quad * 4 + r][n0w + nt * 16 + lane16] = f2bf_raw(acc[nt][r]);
            }
        }
        #pragma unroll
        for (int r = 0; r < 4; ++r) {
            float vs = acc[0][r] * as_att[0] + acc[1][r] * as_att[1]
                     + acc[2][r] * as_att[2] + acc[3][r] * as_att[3];
            float vd = acc[0][r] * ad_att[0] + acc[1][r] * ad_att[1]
                     + acc[2][r] * ad_att[2] + acc[3][r] * ad_att[3];
            vs += __shfl_xor(vs, 1); vs += __shfl_xor(vs, 2);
            vs += __shfl_xor(vs, 4); vs += __shfl_xor(vs, 8);
            vd += __shfl_xor(vd, 1); vd += __shfl_xor(vd, 2);
            vd += __shfl_xor(vd, 4); vd += __shfl_xor(vd, 8);
            if (lane16 == 0) {
                const int row = st * 16 + quad * 4 + r;
                sh_a[0][row][head] = vs;
                sh_a[1][row][head] = vd;
            }
        }

        __syncthreads();

        // cooperative SLAB stores: chunk c in [0,1024): slab sb = c>>7,
        // inner = c&127 = row*4+c4 -> 128 consecutive threads cover 2KB
        // contiguous within one slab (full lines).
        #pragma unroll
        for (int p = 0; p < 2; ++p) {
            const int c = p * 512 + threadIdx.x;
            const int sb = c >> 7;
            const int inner = c & 127;
            const int row = inner >> 2;
            const int c4 = inner & 3;
            if (m0 + row < N) {
                ushort8v v = *(const ushort8v*)&sh_h[row][sb * 32 + c4 * 8];
                *(ushort8v*)(h_out + (size_t)sb * slabN + (size_t)(m0 + row) * 32 + c4 * 8) = v;
            }
        }
        {
            const int t = threadIdx.x;
            if (t < 32) {
                if (m0 + t < N)
                    *(floatx4*)&a_s[(size_t)(m0 + t) * 4] = *(const floatx4*)&sh_a[0][t][0];
            } else if (t >= 64 && t < 96) {
                const int r = t - 64;
                if (m0 + r < N)
                    *(floatx4*)&a_d[(size_t)(m0 + r) * 4] = *(const floatx4*)&sh_a[1][r][0];
            }
        }
    }
}

// K4: single-kernel exclusive scan over 8-way replicated degrees (round-8
// version: 49 x 256-thr blocks, 25-spinner one-hop barrier; 391-spinner
// merged variant was catastrophic — journaled round 9).
__global__ __launch_bounds__(256) void scan_fused_kernel(
    const int* __restrict__ deg8, int* __restrict__ deg,
    int* __restrict__ row_off, int* __restrict__ cursor8,
    int* __restrict__ bsum, int* __restrict__ bbase, int* __restrict__ bsync,
    int N, int nb)
{
    __shared__ int sh[256];
    __shared__ int is_last;
    __shared__ int sbase;
    const int b = blockIdx.x, t = threadIdx.x;
    const int base_i = b * 1024 + t * 4;
    int v[4], ts = 0;
    #pragma unroll
    for (int i = 0; i < 4; ++i) {
        int idx = base_i + i;
        int tot = 0;
        if (idx < N) {
            #pragma unroll
            for (int x = 0; x < 8; ++x) tot += deg8[(size_t)x * N + idx];
        }
        v[i] = tot;
        ts += tot;
    }
    sh[t] = ts; __syncthreads();
    for (int off = 1; off < 256; off <<= 1) {
        int add = (t >= off) ? sh[t - off] : 0;
        __syncthreads();
        sh[t] += add;
        __syncthreads();
    }
    if (t == 255) {
        __hip_atomic_store(&bsum[b], sh[255], __ATOMIC_RELEASE, __HIP_MEMORY_SCOPE_AGENT);
        int arrived = __hip_atomic_fetch_add(&bsync[0], 1, __ATOMIC_ACQ_REL, __HIP_MEMORY_SCOPE_AGENT);
        is_last = (arrived == nb - 1);
    }
    __syncthreads();
    if (is_last) {
        if (nb <= 64) {
            if (t < 64) {
                int val = (t < nb)
                    ? __hip_atomic_load(&bsum[t], __ATOMIC_ACQUIRE, __HIP_MEMORY_SCOPE_AGENT) : 0;
                int incl = val;
                #pragma unroll
                for (int off = 1; off < 64; off <<= 1) {
                    int u = __shfl_up(incl, off);
                    if (t >= off) incl += u;
                }
                if (t < nb)
                    __hip_atomic_store(&bbase[t], incl - val, __ATOMIC_RELEASE, __HIP_MEMORY_SCOPE_AGENT);
            }
        } else if (t == 0) {
            int run = 0;
            for (int i = 0; i < nb; ++i) {
                int s = __hip_atomic_load(&bsum[i], __ATOMIC_ACQUIRE, __HIP_MEMORY_SCOPE_AGENT);
                __hip_atomic_store(&bbase[i], run, __ATOMIC_RELEASE, __HIP_MEMORY_SCOPE_AGENT);
                run += s;
            }
        }
        __syncthreads();
        if (t == 0)
            __hip_atomic_store(&bsync[1], 1, __ATOMIC_RELEASE, __HIP_MEMORY_SCOPE_AGENT);
    }
    if (t == 0) {
        while (__hip_atomic_load(&bsync[1], __ATOMIC_ACQUIRE, __HIP_MEMORY_SCOPE_AGENT) == 0) {}
        sbase = __hip_atomic_load(&bbase[b], __ATOMIC_RELAXED, __HIP_MEMORY_SCOPE_AGENT);
    }
    __syncthreads();
    int run = sbase + sh[t] - ts;
    #pragma unroll
    for (int i = 0; i < 4; ++i) {
        int idx = base_i + i;
        if (idx < N) {
            row_off[idx] = run;
            deg[idx] = v[i];
            int c = run;
            #pragma unroll
            for (int x = 0; x < 8; ++x) {
                cursor8[(size_t)x * N + idx] = c;
                c += deg8[(size_t)x * N + idx];
            }
        }
        run += v[i];
    }
}

// K5: ATOMIC-FREE scatter: pos = static per-copy base + precomputed rank.
// 512-thr / 2048-edge blocks, copy = blockIdx&7 — matches fused count's map.
__global__ __launch_bounds__(512) void scatter_kernel(
    const void* __restrict__ edge, const int* __restrict__ cursor8,
    const int* __restrict__ rank, int* __restrict__ elist,
    const int* __restrict__ flags, int E, int N)
{
    const int base = blockIdx.x * 2048 + threadIdx.x * 4;
    if (base >= E) return;
    const int* mybase = cursor8 + (size_t)(blockIdx.x & 7) * N;
    const int cnt = (E - base < 4) ? (E - base) : 4;
    int s[4], d[4];
    if (flags[3]) {
        const long long* ps = (const long long*)edge + base;
        const long long* pd = (const long long*)edge + E + base;
        #pragma unroll
        for (int k = 0; k < 4; ++k) {
            s[k] = clampN((k < cnt) ? ps[k] : 0, N);
            d[k] = clampN((k < cnt) ? pd[k] : 0, N);
        }
    } else {
        const int* ps = (const int*)edge + base;
        const int* pd = (const int*)edge + E + base;
        #pragma unroll
        for (int k = 0; k < 4; ++k) {
            s[k] = clampN((k < cnt) ? (long long)ps[k] : 0, N);
            d[k] = clampN((k < cnt) ? (long long)pd[k] : 0, N);
        }
    }
    #pragma unroll
    for (int k = 0; k < 4; ++k) {
        if (k < cnt) {
            int pos = mybase[d[k]] + rank[base + k];
            elist[pos] = s[k];
        }
    }
}

// K6: gather-aggregate v5 — XCD-LOCAL SLAB SLICES.
// slice s = blockIdx&7 (round-robin blockIdx->XCD heuristic puts every
// slice-s block on XCD s); block handles 4 nodes x slice s; each wave = one
// node. Per edge, 4 lanes (sub 0..3) read 64B contiguous from slab s
// (h[s][src][32cols], 3.2MB slab resident in that XCD's 4MB L2). 16 edges in
// flight per wave (slot = lane>>2). ssum/acc reduced across the 16 slots via
// shfl_xor 4/8/16/32. slot-0 lanes write the 64B out slice (f32: full 128B).
__global__ __launch_bounds__(256) void aggregate_kernel(
    const int* __restrict__ row_off, const int* __restrict__ deg,
    const int* __restrict__ elist,
    const float* __restrict__ a_s, const float* __restrict__ a_d,
    const unsigned short* __restrict__ h_slab,
    const void* __restrict__ bias, void* __restrict__ out,
    const int* __restrict__ flags, int N)
{
    const int s = blockIdx.x & 7;            // slice == slab == XCD (heuristic)
    const int g = blockIdx.x >> 3;
    const int n = g * 4 + (threadIdx.x >> 6);
    if (n >= N) return;
    const int lane = threadIdx.x & 63;
    const int slot = lane >> 2;              // edge slot 0..15
    const int sub  = lane & 3;               // 8-col group within the slice
    const int head = s >> 1;                 // slice covers cols [s*32, s*32+32)
    const size_t slabN = (size_t)N * 32;
    const unsigned short* hs = h_slab + (size_t)s * slabN;

    const int dn = deg[n];
    const int row = row_off[n];
    const float adn = a_d[n * 4 + head];
    const float self_logit = lrelu(a_s[n * 4 + head] + adn);

    float acc[8];
    {
        const uint4v hv = *(const uint4v*)(hs + (size_t)n * 32 + sub * 8);
        #pragma unroll
        for (int w = 0; w < 4; ++w) {
            acc[2 * w]     = (slot == 0) ? asf(hv[w] << 16) : 0.f;
            acc[2 * w + 1] = (slot == 0) ? asf(hv[w] & 0xffff0000u) : 0.f;
        }
    }
    float ssum = (slot == 0) ? 1.f : 0.f;    // self-loop: p = exp(0) = 1

    // 16 edges in flight; next group's idx/as/h prefetched during consume
    bool v0 = slot < dn;
    int s0 = v0 ? elist[row + slot] : n;
    float as0 = a_s[s0 * 4 + head];
    uint4v h0 = *(const uint4v*)(hs + (size_t)s0 * 32 + sub * 8);

    for (int c0 = 0; c0 < dn; c0 += 16) {
        const int e1 = c0 + 16 + slot;
        const bool v1 = e1 < dn;
        const int s1 = v1 ? elist[row + e1] : n;
        const float as1 = a_s[s1 * 4 + head];
        const uint4v h1 = *(const uint4v*)(hs + (size_t)s1 * 32 + sub * 8);

        float p = v0 ? __expf(lrelu(as0 + adn) - self_logit) : 0.f;
        ssum += p;
        #pragma unroll
        for (int w = 0; w < 4; ++w) {
            acc[2 * w]     += p * asf(h0[w] << 16);
            acc[2 * w + 1] += p * asf(h0[w] & 0xffff0000u);
        }
        v0 = v1; s0 = s1; as0 = as1; h0 = h1;
    }

    // reduce across the 16 slots (lanes sharing the same sub)
    #pragma unroll
    for (int j = 0; j < 8; ++j) {
        acc[j] += __shfl_xor(acc[j], 4);
        acc[j] += __shfl_xor(acc[j], 8);
        acc[j] += __shfl_xor(acc[j], 16);
        acc[j] += __shfl_xor(acc[j], 32);
    }
    ssum += __shfl_xor(ssum, 4);
    ssum += __shfl_xor(ssum, 8);
    ssum += __shfl_xor(ssum, 16);
    ssum += __shfl_xor(ssum, 32);

    if (slot == 0) {
        const float inv = 1.f / ssum;
        const int col0 = s * 32 + sub * 8;
        const int bf32 = flags[2];
        float o[8];
        #pragma unroll
        for (int k = 0; k < 8; ++k)
            o[k] = acc[k] * inv + ldf(bias, col0 + k, bf32);
        if (flags[0]) {
            float* op = (float*)out + (size_t)n * 256 + col0;
            __builtin_nontemporal_store((floatx4){o[0], o[1], o[2], o[3]}, (floatx4*)op);
            __builtin_nontemporal_store((floatx4){o[4], o[5], o[6], o[7]}, (floatx4*)(op + 4));
        } else {
            ushort8v ov;
            #pragma unroll
            for (int k = 0; k < 8; ++k) ov[k] = f2bf_raw(o[k]);
            __builtin_nontemporal_store(ov,
                (ushort8v*)((unsigned short*)out + (size_t)n * 256 + col0));
        }
    }
}

// Diagnostic: ws too small -> absmax tells us ws_MB*1000.
__global__ __launch_bounds__(256) void sentinel_kernel(unsigned short* out, size_t n, float v) {
    size_t i = (size_t)blockIdx.x * 256 + threadIdx.x;
    if (i < n) out[i] = f2bf_raw(v);
}

extern "C" void kernel_launch(void* const* d_in, const int* in_sizes, int n_in,
                              void* d_out, int out_size, void* d_ws, size_t ws_size,
                              hipStream_t stream) {
    const void* x       = d_in[0];
    const void* edge    = d_in[1];
    const void* W       = d_in[2];
    const void* att_src = d_in[3];
    const void* att_dst = d_in[4];
    const void* bias    = d_in[5];

    const int N = in_sizes[0] / 256;   // 50000
    const int E = in_sizes[1] / 2;     // 800000

    char* ws = (char*)d_ws;
    size_t off = 256;
    int*   flags   = (int*)ws;
    float* a_s     = (float*)(ws + off); off += (size_t)N * 4 * sizeof(float);
    float* a_d     = (float*)(ws + off); off += (size_t)N * 4 * sizeof(float);
    int*   deg     = (int*)(ws + off);   off += (size_t)N * sizeof(int);
    int*   row_off = (int*)(ws + off);   off += (size_t)N * sizeof(int);
    int*   bsum    = (int*)(ws + off);   off += 256 * sizeof(int);
    int*   bbase   = (int*)(ws + off);   off += 256 * sizeof(int);
    int*   bsync   = (int*)(ws + off);   off += 256 * sizeof(int);
    unsigned short* Wt = (unsigned short*)(ws + off); off += 65536 * sizeof(unsigned short);
    // elist (E ints) overlays deg8 (8N ints): deg8 is dead after the scan,
    // elist is written only by scatter (after the scan). E*4 >= 8N*4 here.
    size_t elist_bytes = (size_t)E * sizeof(int);
    size_t deg8_bytes  = (size_t)8 * N * sizeof(int);
    int*   elist   = (int*)(ws + off);
    int*   deg8    = (int*)(ws + off);   off += (elist_bytes > deg8_bytes ? elist_bytes : deg8_bytes);
    int*   cursor8 = (int*)(ws + off);   off += deg8_bytes;
    int*   rank    = (int*)(ws + off);   off += (size_t)E * sizeof(int);
    unsigned short* h_ws = (unsigned short*)(ws + off);   // 8 slabs of [N][32]
    const size_t need = off + (size_t)N * 256 * sizeof(unsigned short);

    if (ws_size < need) {
        float v = (float)(ws_size >> 20) * 1000.0f;
        size_t n = (size_t)out_size;
        sentinel_kernel<<<(unsigned)((n + 255) / 256), 256, 0, stream>>>(
            (unsigned short*)d_out, n, v);
        return;
    }

    int edge_words = (2 * E < 512) ? 2 * E : 512;
    prep_kernel<<<256, 256, 0, stream>>>(
        W, Wt, (const unsigned short*)x,
        (const unsigned short*)att_src, (const unsigned short*)att_dst,
        (const unsigned*)edge, flags, edge_words, deg8, bsync, 8 * N);

    const int ntiles = (N + 31) / 32;
    const int ngemm = 1024;
    const int ncount = (E + 2047) / 2048;        // 391 count blocks (2048 edges each)
    const int ntotal = ngemm + ncount;
    gemm_count_kernel<<<ntotal, 512, 0, stream>>>(
        x, Wt, att_src, att_dst, h_ws, a_s, a_d, edge, deg8, rank,
        flags, N, E, ntiles, ngemm, ncount, ntotal);

    const int nb = (N + 1023) / 1024;            // 49 scan chunks
    scan_fused_kernel<<<nb, 256, 0, stream>>>(
        deg8, deg, row_off, cursor8, bsum, bbase, bsync, N, nb);

    scatter_kernel<<<ncount, 512, 0, stream>>>(edge, cursor8, rank, elist, flags, E, N);

    const int agg_blocks = 8 * ((N + 3) / 4);    // (node-group, slice) grid
    aggregate_kernel<<<agg_blocks, 256, 0, stream>>>(
        row_off, deg, elist, a_s, a_d, h_ws, bias, d_out, flags, N);
}

// Round 12
// 242.324 us; speedup vs baseline: 1.4100x; 1.4100x over previous
//
#include <hip/hip_runtime.h>
#include <hip/hip_bf16.h>

#define NEG_SLOPE 0.2f
#define HPAD 264   // 256 + 8 ushort pad: breaks pow-2 LDS bank stride

typedef short short8 __attribute__((ext_vector_type(8)));
typedef float floatx4 __attribute__((ext_vector_type(4)));
typedef unsigned short ushort8v __attribute__((ext_vector_type(8)));
typedef unsigned short ushort4v __attribute__((ext_vector_type(4)));
typedef unsigned int uint4v __attribute__((ext_vector_type(4)));

__device__ __forceinline__ float bf2f_raw(unsigned short u) {
    union { float f; unsigned u; } c; c.u = ((unsigned)u) << 16; return c.f;
}
__device__ __forceinline__ float asf(unsigned u) {
    union { float f; unsigned u; } c; c.u = u; return c.f;
}
__device__ __forceinline__ unsigned short f2bf_raw(float f) {
    union { float f; unsigned u; } c; c.f = f;
    unsigned u = c.u;
    u += 0x7FFFu + ((u >> 16) & 1u);   // round-to-nearest-even
    return (unsigned short)(u >> 16);
}
__device__ __forceinline__ float ldf(const void* p, size_t i, int f32) {
    return f32 ? ((const float*)p)[i] : bf2f_raw(((const unsigned short*)p)[i]);
}
__device__ __forceinline__ unsigned short ldbf(const void* p, size_t i, int f32) {
    return f32 ? f2bf_raw(((const float*)p)[i]) : ((const unsigned short*)p)[i];
}
__device__ __forceinline__ int clampN(long long v, int N) {
    if (v < 0) v = 0;
    if (v >= N) v = N - 1;
    return (int)v;
}
__device__ __forceinline__ float lrelu(float v) { return v > 0.f ? v : NEG_SLOPE * v; }

// async global->LDS, 16B per lane (guide §5: width 16; LDS dest is
// wave-uniform base + lane*16 — callers must pass the wave's uniform base).
__device__ __forceinline__ void glds16(const void* g, void* l) {
    __builtin_amdgcn_global_load_lds(
        (const __attribute__((address_space(1))) void*)g,
        (__attribute__((address_space(3))) void*)l, 16, 0, 0);
}

// K0: prep = dtype detect + W transpose + workspace zeroing, ONE kernel
// (round-9 merge, proven clean). Redundant per-block W-dtype detection (8KB
// re-read, L2-served; no cross-block sync). Block 0 writes flags[0..3].
__global__ __launch_bounds__(256) void prep_kernel(
    const void* __restrict__ W, unsigned short* __restrict__ Wt,
    const unsigned short* __restrict__ x,
    const unsigned short* __restrict__ as_, const unsigned short* __restrict__ ad_,
    const unsigned* __restrict__ edge_w, int* __restrict__ flags, int edge_words,
    int* __restrict__ deg8, int* __restrict__ bsync, int N8)
{
    __shared__ float sm[256];
    __shared__ unsigned su[256];
    const int t = threadIdx.x;
    const int i = blockIdx.x * 256 + t;   // 65536 total

    #pragma unroll
    for (int j = 0; j < 7; ++j) {          // 458752 >= 8*N = 400000
        int z = i + j * 65536;
        if (z < N8) deg8[z] = 0;
    }
    if (i < 256) bsync[i] = 0;

    float mw = 0.f;
    for (int k = t; k < 4096; k += 256) {
        float v = fabsf(bf2f_raw(((const unsigned short*)W)[k]));
        mw = fmaxf(mw, (v == v && v < 3e38f) ? v : 1e9f);
    }
    sm[t] = mw; __syncthreads();
    for (int s = 128; s; s >>= 1) { if (t < s) sm[t] = fmaxf(sm[t], sm[t + s]); __syncthreads(); }
    const int wf32 = sm[0] > 100.f;
    __syncthreads();

    if (blockIdx.x == 0) {
        float mx = 0.f, ma = 0.f;
        for (int k = t; k < 4096; k += 256) {
            float v = fabsf(bf2f_raw(x[k]));
            mx = fmaxf(mx, (v == v && v < 3e38f) ? v : 1e9f);
        }
        {
            float v1 = fabsf(bf2f_raw(as_[t]));
            float v2 = fabsf(bf2f_raw(ad_[t]));
            v1 = (v1 == v1 && v1 < 3e38f) ? v1 : 1e9f;
            v2 = (v2 == v2 && v2 < 3e38f) ? v2 : 1e9f;
            ma = fmaxf(v1, v2);
        }
        unsigned ow = 0;
        {
            int k = 2 * t + 1;
            if (k < edge_words) ow = edge_w[k];
        }
        sm[t] = mx; __syncthreads();
        for (int s = 128; s; s >>= 1) { if (t < s) sm[t] = fmaxf(sm[t], sm[t + s]); __syncthreads(); }
        if (t == 0) flags[0] = sm[0] > 100.f;
        __syncthreads();
        sm[t] = ma; __syncthreads();
        for (int s = 128; s; s >>= 1) { if (t < s) sm[t] = fmaxf(sm[t], sm[t + s]); __syncthreads(); }
        if (t == 0) flags[2] = sm[0] > 100.f;
        __syncthreads();
        su[t] = ow; __syncthreads();
        for (int s = 128; s; s >>= 1) { if (t < s) su[t] |= su[t + s]; __syncthreads(); }
        if (t == 0) { flags[3] = (su[0] == 0u); flags[1] = wf32; }
    }

    int j = i & 7;
    int l = (i >> 3) & 63;
    int ks = (i >> 9) & 7;
    int c = i >> 12;
    int k = ks * 32 + (l >> 4) * 8 + j;
    int n = c * 16 + (l & 15);
    Wt[i] = ldbf(W, (size_t)k * 256 + n, wf32);
}

// K1: MFMA gemm INTERLEAVED with count (round-8 Bresenham role-spread, proven).
// v12 gemm: x-tile (32 rows x 512B = 16KB) staged into LDS ONCE per block via
// global_load_lds width=16 (guide G15; compiler never auto-emits it), then all
// 8 waves read fa via ds_read_b128. Removes (a) the per-wave serial global
// load->MFMA chain that kept the gemm latency-bound (rounds 6-7: pipes <10%,
// traffic ideal) and (b) the 4x redundant x-row reads by the 4 head-waves.
// Swizzle: phys = addr ^ ((row&7)<<4), applied on the GLOBAL SOURCE for the
// glds (linear LDS dest, rule #21) and on the ds_read addr -> stride-512B fa
// reads drop from 16-way to 2-way bank conflict (free). f32-x path reg-stages
// with converts to the same swizzled layout.
__global__ __launch_bounds__(512) void gemm_count_kernel(
    const void* __restrict__ x, const unsigned short* __restrict__ Wt,
    const void* __restrict__ att_src, const void* __restrict__ att_dst,
    unsigned short* __restrict__ h_out, float* __restrict__ a_s, float* __restrict__ a_d,
    const void* __restrict__ edge, int* __restrict__ deg8, int* __restrict__ rank,
    const int* __restrict__ flags, int N, int E, int ntiles,
    int ngemm, int ncount, int ntotal)
{
    const unsigned long long bi = blockIdx.x;
    const unsigned before = (unsigned)((bi * (unsigned long long)ncount) / ntotal);
    const unsigned after  = (unsigned)(((bi + 1) * (unsigned long long)ncount) / ntotal);

    if (after != before) {
        // ---- count role: block index cb = before ----
        const int cb = (int)before;
        const int base = cb * 2048 + threadIdx.x * 4;
        if (base >= E) return;
        int* my = deg8 + (size_t)(cb & 7) * N;
        const int cnt = (E - base < 4) ? (E - base) : 4;
        int d[4];
        if (flags[3]) {
            const long long* p = (const long long*)edge + E + base;
            #pragma unroll
            for (int k = 0; k < 4; ++k) d[k] = clampN((k < cnt) ? p[k] : 0, N);
        } else {
            const int* p = (const int*)edge + E + base;
            #pragma unroll
            for (int k = 0; k < 4; ++k) d[k] = clampN((k < cnt) ? (long long)p[k] : 0, N);
        }
        int r[4] = {0, 0, 0, 0};
        #pragma unroll
        for (int k = 0; k < 4; ++k)
            if (k < cnt) r[k] = atomicAdd(&my[d[k]], 1);
        #pragma unroll
        for (int k = 0; k < 4; ++k)
            if (k < cnt) rank[base + k] = r[k];
        return;
    }

    // ---- gemm role: block index gb = bi - before ----
    const int gb = (int)(bi - before);

    __shared__ unsigned short sh_x[8192];       // 16KB x tile, swizzled layout
    __shared__ unsigned short sh_h[32][HPAD];   // 32-row tile, all 256 cols
    __shared__ float sh_a[2][32][4];            // [as/ad][row][head]

    const int tid = threadIdx.x;
    const int w = tid >> 6;                     // wave 0..7
    const int head = w >> 1;
    const int st = w & 1;                       // row-subtile 0/1
    const int l = tid & 63;
    const int lane16 = l & 15;
    const int quad = l >> 4;
    const int xf = flags[0], af = flags[2];
    const int n0w = head * 64;

    float as_att[4], ad_att[4];
    #pragma unroll
    for (int nt = 0; nt < 4; ++nt) {
        as_att[nt] = ldf(att_src, n0w + nt * 16 + lane16, af);
        ad_att[nt] = ldf(att_dst, n0w + nt * 16 + lane16, af);
    }

    const int rowl = st * 16 + lane16;          // this wave's LDS row 0..31
    const int swl = (rowl & 7) << 4;
    char* const xb = (char*)sh_x;

    for (int tile = gb; tile < ntiles; tile += ngemm) {
        const int m0 = tile * 32;

        // ---- stage x tile into LDS (barrier: prev iter's sh_x reads + sh_h
        //      cooperative-store reads both complete before overwrite) ----
        __syncthreads();
        if (!xf) {
            // glds: 2 issues x 512 threads x 16B. chunk t16 = linear 16B slot;
            // source in-row offset pre-swizzled so LDS[linear] ends up holding
            // the swizzled layout (involution).
            #pragma unroll
            for (int p = 0; p < 2; ++p) {
                const int t16 = p * 512 + tid;
                const int rowb = t16 >> 5;          // 32 chunks per 512B row
                const int off = (t16 & 31) * 16;
                int srow = m0 + rowb; if (srow >= N) srow = N - 1;
                const char* g = (const char*)x + (size_t)srow * 512
                              + (off ^ ((rowb & 7) << 4));
                // wave-uniform LDS base: chunks (p*512 + w*64) .. +63
                glds16(g, xb + (size_t)(p * 512 + w * 64) * 16);
            }
        } else {
            // f32 x: reg-stage + convert, write same swizzled layout
            #pragma unroll
            for (int p = 0; p < 2; ++p) {
                const int t16 = p * 512 + tid;
                const int rowb = t16 >> 5;
                const int off = (t16 & 31) * 16;
                int srow = m0 + rowb; if (srow >= N) srow = N - 1;
                const int c0 = (off ^ ((rowb & 7) << 4)) >> 1;   // src col
                const float* fp = (const float*)x + (size_t)srow * 256 + c0;
                ushort8v v;
                #pragma unroll
                for (int j = 0; j < 8; ++j) v[j] = f2bf_raw(fp[j]);
                *(ushort8v*)(xb + (size_t)t16 * 16) = v;
            }
        }
        __syncthreads();   // staging complete (compiler drains vmcnt here)

        floatx4 acc[4];
        #pragma unroll
        for (int nt = 0; nt < 4; ++nt) acc[nt] = (floatx4){0.f, 0.f, 0.f, 0.f};

        const unsigned short* wp0 = Wt + (((size_t)head * 32) * 64 + l) * 8;

        #pragma unroll
        for (int half = 0; half < 2; ++half) {
            short8 fa[4];
            #pragma unroll
            for (int k4 = 0; k4 < 4; ++k4) {
                const int A = rowl * 512 + half * 256 + k4 * 64 + quad * 16;
                fa[k4] = *(const short8*)(xb + (A ^ swl));
            }
            #pragma unroll
            for (int k4 = 0; k4 < 4; ++k4) {
                const unsigned short* wp = wp0 + (size_t)(half * 4 + k4) * 512;
                #pragma unroll
                for (int nt = 0; nt < 4; ++nt) {
                    short8 fb = *(const short8*)(wp + nt * 4096);
                    acc[nt] = __builtin_amdgcn_mfma_f32_16x16x32_bf16(fa[k4], fb, acc[nt], 0, 0, 0);
                }
            }
        }

        __syncthreads();   // WAR: prev iteration's sh_h coop-store reads done

        #pragma unroll
        for (int nt = 0; nt < 4; ++nt) {
            #pragma unroll
            for (int r = 0; r < 4; ++r) {
                sh_h[st * 16 + quad * 4 + r][n0w + nt * 16 + lane16] = f2bf_raw(acc[nt][r]);
            }
        }
        #pragma unroll
        for (int r = 0; r < 4; ++r) {
            float vs = acc[0][r] * as_att[0] + acc[1][r] * as_att[1]
                     + acc[2][r] * as_att[2] + acc[3][r] * as_att[3];
            float vd = acc[0][r] * ad_att[0] + acc[1][r] * ad_att[1]
                     + acc[2][r] * ad_att[2] + acc[3][r] * ad_att[3];
            vs += __shfl_xor(vs, 1); vs += __shfl_xor(vs, 2);
            vs += __shfl_xor(vs, 4); vs += __shfl_xor(vs, 8);
            vd += __shfl_xor(vd, 1); vd += __shfl_xor(vd, 2);
            vd += __shfl_xor(vd, 4); vd += __shfl_xor(vd, 8);
            if (lane16 == 0) {
                const int row = st * 16 + quad * 4 + r;
                sh_a[0][row][head] = vs;
                sh_a[1][row][head] = vd;
            }
        }

        __syncthreads();

        // cooperative full-line stores: 2 passes x 512 threads x 16B
        #pragma unroll
        for (int p = 0; p < 2; ++p) {
            const int c = p * 512 + tid;           // 16B chunk id, 1024 total
            const int row = c >> 5;
            const int ch = c & 31;
            if (m0 + row < N) {
                ushort8v v = *(const ushort8v*)&sh_h[row][ch * 8];
                *(ushort8v*)(h_out + (size_t)(m0 + row) * 256 + ch * 8) = v;
            }
        }
        {
            if (tid < 32) {
                if (m0 + tid < N)
                    *(floatx4*)&a_s[(size_t)(m0 + tid) * 4] = *(const floatx4*)&sh_a[0][tid][0];
            } else if (tid >= 64 && tid < 96) {
                const int r = tid - 64;
                if (m0 + r < N)
                    *(floatx4*)&a_d[(size_t)(m0 + r) * 4] = *(const floatx4*)&sh_a[1][r][0];
            }
        }
    }
}

// K4: single-kernel exclusive scan over 8-way replicated degrees (round-8
// version: 49 x 256-thr blocks, 25-spinner one-hop barrier; 391-spinner
// merged variant was catastrophic — journaled round 9).
__global__ __launch_bounds__(256) void scan_fused_kernel(
    const int* __restrict__ deg8, int* __restrict__ deg,
    int* __restrict__ row_off, int* __restrict__ cursor8,
    int* __restrict__ bsum, int* __restrict__ bbase, int* __restrict__ bsync,
    int N, int nb)
{
    __shared__ int sh[256];
    __shared__ int is_last;
    __shared__ int sbase;
    const int b = blockIdx.x, t = threadIdx.x;
    const int base_i = b * 1024 + t * 4;
    int v[4], ts = 0;
    #pragma unroll
    for (int i = 0; i < 4; ++i) {
        int idx = base_i + i;
        int tot = 0;
        if (idx < N) {
            #pragma unroll
            for (int x = 0; x < 8; ++x) tot += deg8[(size_t)x * N + idx];
        }
        v[i] = tot;
        ts += tot;
    }
    sh[t] = ts; __syncthreads();
    for (int off = 1; off < 256; off <<= 1) {
        int add = (t >= off) ? sh[t - off] : 0;
        __syncthreads();
        sh[t] += add;
        __syncthreads();
    }
    if (t == 255) {
        __hip_atomic_store(&bsum[b], sh[255], __ATOMIC_RELEASE, __HIP_MEMORY_SCOPE_AGENT);
        int arrived = __hip_atomic_fetch_add(&bsync[0], 1, __ATOMIC_ACQ_REL, __HIP_MEMORY_SCOPE_AGENT);
        is_last = (arrived == nb - 1);
    }
    __syncthreads();
    if (is_last) {
        if (nb <= 64) {
            if (t < 64) {
                int val = (t < nb)
                    ? __hip_atomic_load(&bsum[t], __ATOMIC_ACQUIRE, __HIP_MEMORY_SCOPE_AGENT) : 0;
                int incl = val;
                #pragma unroll
                for (int off = 1; off < 64; off <<= 1) {
                    int u = __shfl_up(incl, off);
                    if (t >= off) incl += u;
                }
                if (t < nb)
                    __hip_atomic_store(&bbase[t], incl - val, __ATOMIC_RELEASE, __HIP_MEMORY_SCOPE_AGENT);
            }
        } else if (t == 0) {
            int run = 0;
            for (int i = 0; i < nb; ++i) {
                int s = __hip_atomic_load(&bsum[i], __ATOMIC_ACQUIRE, __HIP_MEMORY_SCOPE_AGENT);
                __hip_atomic_store(&bbase[i], run, __ATOMIC_RELEASE, __HIP_MEMORY_SCOPE_AGENT);
                run += s;
            }
        }
        __syncthreads();
        if (t == 0)
            __hip_atomic_store(&bsync[1], 1, __ATOMIC_RELEASE, __HIP_MEMORY_SCOPE_AGENT);
    }
    if (t == 0) {
        while (__hip_atomic_load(&bsync[1], __ATOMIC_ACQUIRE, __HIP_MEMORY_SCOPE_AGENT) == 0) {}
        sbase = __hip_atomic_load(&bbase[b], __ATOMIC_RELAXED, __HIP_MEMORY_SCOPE_AGENT);
    }
    __syncthreads();
    int run = sbase + sh[t] - ts;
    #pragma unroll
    for (int i = 0; i < 4; ++i) {
        int idx = base_i + i;
        if (idx < N) {
            row_off[idx] = run;
            deg[idx] = v[i];
            int c = run;
            #pragma unroll
            for (int x = 0; x < 8; ++x) {
                cursor8[(size_t)x * N + idx] = c;
                c += deg8[(size_t)x * N + idx];
            }
        }
        run += v[i];
    }
}

// K5: ATOMIC-FREE scatter: pos = static per-copy base + precomputed rank.
// 512-thr / 2048-edge blocks, copy = blockIdx&7 — matches fused count's map.
__global__ __launch_bounds__(512) void scatter_kernel(
    const void* __restrict__ edge, const int* __restrict__ cursor8,
    const int* __restrict__ rank, int* __restrict__ elist,
    const int* __restrict__ flags, int E, int N)
{
    const int base = blockIdx.x * 2048 + threadIdx.x * 4;
    if (base >= E) return;
    const int* mybase = cursor8 + (size_t)(blockIdx.x & 7) * N;
    const int cnt = (E - base < 4) ? (E - base) : 4;
    int s[4], d[4];
    if (flags[3]) {
        const long long* ps = (const long long*)edge + base;
        const long long* pd = (const long long*)edge + E + base;
        #pragma unroll
        for (int k = 0; k < 4; ++k) {
            s[k] = clampN((k < cnt) ? ps[k] : 0, N);
            d[k] = clampN((k < cnt) ? pd[k] : 0, N);
        }
    } else {
        const int* ps = (const int*)edge + base;
        const int* pd = (const int*)edge + E + base;
        #pragma unroll
        for (int k = 0; k < 4; ++k) {
            s[k] = clampN((k < cnt) ? (long long)ps[k] : 0, N);
            d[k] = clampN((k < cnt) ? (long long)pd[k] : 0, N);
        }
    }
    #pragma unroll
    for (int k = 0; k < 4; ++k) {
        if (k < cnt) {
            int pos = mybase[d[k]] + rank[base + k];
            elist[pos] = s[k];
        }
    }
}

// K6: gather-aggregate, one WAVE per node (round-7/10 proven 71.5us version;
// round-11 slab-slice variant cut FETCH 3.4x but 8x'd per-node fixed overhead
// -> 173us, reverted. This stage sits at ~2.9 MB/us L2-miss service for
// random 512B gathers from the 25.6MB h table — the L2-miss path, not HBM,
// is the ceiling at this layout).
__global__ __launch_bounds__(256) void aggregate_kernel(
    const int* __restrict__ row_off, const int* __restrict__ deg,
    const int* __restrict__ elist,
    const float* __restrict__ a_s, const float* __restrict__ a_d,
    const unsigned short* __restrict__ h_ws,
    const void* __restrict__ bias, void* __restrict__ out,
    const int* __restrict__ flags, int N)
{
    const int n = blockIdx.x * 4 + (threadIdx.x >> 6);
    if (n >= N) return;
    const int lane = threadIdx.x & 63;
    const int q = lane >> 4;        // edge slot 0..3 within a group of 4
    const int li = lane & 15;
    const int head = li >> 2;       // 16 cols/lane -> 4 lanes per head
    const int col0 = li * 16;

    const int dn = deg[n];
    const int row = row_off[n];
    const float adn = a_d[n * 4 + head];
    const float self_logit = lrelu(a_s[n * 4 + head] + adn);

    float acc[16];
    {
        const uint4v* hp = (const uint4v*)(h_ws + (size_t)n * 256 + col0);
        uint4v ha = hp[0], hb = hp[1];
        #pragma unroll
        for (int w = 0; w < 4; ++w) {
            acc[2 * w]         = (q == 0) ? asf(ha[w] << 16) : 0.f;
            acc[2 * w + 1]     = (q == 0) ? asf(ha[w] & 0xffff0000u) : 0.f;
            acc[8 + 2 * w]     = (q == 0) ? asf(hb[w] << 16) : 0.f;
            acc[8 + 2 * w + 1] = (q == 0) ? asf(hb[w] & 0xffff0000u) : 0.f;
        }
    }
    float ssum = (q == 0) ? 1.f : 0.f;   // self-loop: p = exp(0) = 1

    // prologue: stage A = edges [0..3], B = [4..7]; index prefetch C, D
    float asA, asB;
    uint4v hA0, hA1, hB0, hB1;
    int sC, sD;
    {
        int e0 = q, e1 = 4 + q, e2 = 8 + q, e3 = 12 + q;
        int s0 = (e0 < dn) ? elist[row + e0] : n;
        int s1 = (e1 < dn) ? elist[row + e1] : n;
        sC = (e2 < dn) ? elist[row + e2] : n;
        sD = (e3 < dn) ? elist[row + e3] : n;
        asA = a_s[s0 * 4 + head];
        asB = a_s[s1 * 4 + head];
        const uint4v* pA = (const uint4v*)(h_ws + (size_t)s0 * 256 + col0);
        const uint4v* pB = (const uint4v*)(h_ws + (size_t)s1 * 256 + col0);
        hA0 = pA[0]; hA1 = pA[1];
        hB0 = pB[0]; hB1 = pB[1];
    }

    for (int c0 = 0; c0 < dn; c0 += 8) {
        // consume A (edges c0+q)
        {
            float p = __expf(lrelu(asA + adn) - self_logit);
            p = (c0 + q < dn) ? p : 0.f;
            ssum += p;
            #pragma unroll
            for (int w = 0; w < 4; ++w) {
                acc[2 * w]         += p * asf(hA0[w] << 16);
                acc[2 * w + 1]     += p * asf(hA0[w] & 0xffff0000u);
                acc[8 + 2 * w]     += p * asf(hA1[w] << 16);
                acc[8 + 2 * w + 1] += p * asf(hA1[w] & 0xffff0000u);
            }
        }
        // refill A <- group c0+8 (index sC); prefetch index c0+16
        {
            asA = a_s[sC * 4 + head];
            const uint4v* p = (const uint4v*)(h_ws + (size_t)sC * 256 + col0);
            hA0 = p[0]; hA1 = p[1];
            int e = c0 + 16 + q;
            sC = (e < dn) ? elist[row + e] : n;
        }
        // consume B (edges c0+4+q)
        {
            float p = __expf(lrelu(asB + adn) - self_logit);
            p = (c0 + 4 + q < dn) ? p : 0.f;
            ssum += p;
            #pragma unroll
            for (int w = 0; w < 4; ++w) {
                acc[2 * w]         += p * asf(hB0[w] << 16);
                acc[2 * w + 1]     += p * asf(hB0[w] & 0xffff0000u);
                acc[8 + 2 * w]     += p * asf(hB1[w] << 16);
                acc[8 + 2 * w + 1] += p * asf(hB1[w] & 0xffff0000u);
            }
        }
        // refill B <- group c0+12 (index sD); prefetch index c0+20
        {
            asB = a_s[sD * 4 + head];
            const uint4v* p = (const uint4v*)(h_ws + (size_t)sD * 256 + col0);
            hB0 = p[0]; hB1 = p[1];
            int e = c0 + 20 + q;
            sD = (e < dn) ? elist[row + e] : n;
        }
    }

    // reduce across the 4 quarters
    #pragma unroll
    for (int j = 0; j < 16; ++j) {
        acc[j] += __shfl_xor(acc[j], 16);
        acc[j] += __shfl_xor(acc[j], 32);
    }
    float stot = ssum + __shfl_xor(ssum, 16);
    stot += __shfl_xor(stot, 32);

    // all 64 lanes write: lane covers cols [col0+q*4, col0+q*4+4)
    const float inv = 1.f / stot;
    const int j0 = q * 4;
    const int bf32 = flags[2];
    float o[4];
    #pragma unroll
    for (int k = 0; k < 4; ++k)
        o[k] = acc[j0 + k] * inv + ldf(bias, col0 + j0 + k, bf32);
    if (flags[0]) {
        float* op = (float*)out + (size_t)n * 256 + col0 + j0;
        __builtin_nontemporal_store((floatx4){o[0], o[1], o[2], o[3]}, (floatx4*)op);
    } else {
        ushort4v ov;
        #pragma unroll
        for (int k = 0; k < 4; ++k) ov[k] = f2bf_raw(o[k]);
        __builtin_nontemporal_store(ov,
            (ushort4v*)((unsigned short*)out + (size_t)n * 256 + col0 + j0));
    }
}

// Diagnostic: ws too small -> absmax tells us ws_MB*1000.
__global__ __launch_bounds__(256) void sentinel_kernel(unsigned short* out, size_t n, float v) {
    size_t i = (size_t)blockIdx.x * 256 + threadIdx.x;
    if (i < n) out[i] = f2bf_raw(v);
}

extern "C" void kernel_launch(void* const* d_in, const int* in_sizes, int n_in,
                              void* d_out, int out_size, void* d_ws, size_t ws_size,
                              hipStream_t stream) {
    const void* x       = d_in[0];
    const void* edge    = d_in[1];
    const void* W       = d_in[2];
    const void* att_src = d_in[3];
    const void* att_dst = d_in[4];
    const void* bias    = d_in[5];

    const int N = in_sizes[0] / 256;   // 50000
    const int E = in_sizes[1] / 2;     // 800000

    char* ws = (char*)d_ws;
    size_t off = 256;
    int*   flags   = (int*)ws;
    float* a_s     = (float*)(ws + off); off += (size_t)N * 4 * sizeof(float);
    float* a_d     = (float*)(ws + off); off += (size_t)N * 4 * sizeof(float);
    int*   deg     = (int*)(ws + off);   off += (size_t)N * sizeof(int);
    int*   row_off = (int*)(ws + off);   off += (size_t)N * sizeof(int);
    int*   bsum    = (int*)(ws + off);   off += 256 * sizeof(int);
    int*   bbase   = (int*)(ws + off);   off += 256 * sizeof(int);
    int*   bsync   = (int*)(ws + off);   off += 256 * sizeof(int);
    unsigned short* Wt = (unsigned short*)(ws + off); off += 65536 * sizeof(unsigned short);
    // elist (E ints) overlays deg8 (8N ints): deg8 is dead after the scan,
    // elist is written only by scatter (after the scan). E*4 >= 8N*4 here.
    size_t elist_bytes = (size_t)E * sizeof(int);
    size_t deg8_bytes  = (size_t)8 * N * sizeof(int);
    int*   elist   = (int*)(ws + off);
    int*   deg8    = (int*)(ws + off);   off += (elist_bytes > deg8_bytes ? elist_bytes : deg8_bytes);
    int*   cursor8 = (int*)(ws + off);   off += deg8_bytes;
    int*   rank    = (int*)(ws + off);   off += (size_t)E * sizeof(int);
    unsigned short* h_ws = (unsigned short*)(ws + off);
    const size_t need = off + (size_t)N * 256 * sizeof(unsigned short);

    if (ws_size < need) {
        float v = (float)(ws_size >> 20) * 1000.0f;
        size_t n = (size_t)out_size;
        sentinel_kernel<<<(unsigned)((n + 255) / 256), 256, 0, stream>>>(
            (unsigned short*)d_out, n, v);
        return;
    }

    int edge_words = (2 * E < 512) ? 2 * E : 512;
    prep_kernel<<<256, 256, 0, stream>>>(
        W, Wt, (const unsigned short*)x,
        (const unsigned short*)att_src, (const unsigned short*)att_dst,
        (const unsigned*)edge, flags, edge_words, deg8, bsync, 8 * N);

    const int ntiles = (N + 31) / 32;
    const int ngemm = 1024;
    const int ncount = (E + 2047) / 2048;        // 391 count blocks (2048 edges each)
    const int ntotal = ngemm + ncount;
    gemm_count_kernel<<<ntotal, 512, 0, stream>>>(
        x, Wt, att_src, att_dst, h_ws, a_s, a_d, edge, deg8, rank,
        flags, N, E, ntiles, ngemm, ncount, ntotal);

    const int nb = (N + 1023) / 1024;            // 49 scan chunks
    scan_fused_kernel<<<nb, 256, 0, stream>>>(
        deg8, deg, row_off, cursor8, bsum, bbase, bsync, N, nb);

    scatter_kernel<<<ncount, 512, 0, stream>>>(edge, cursor8, rank, elist, flags, E, N);

    aggregate_kernel<<<(N + 3) / 4, 256, 0, stream>>>(
        row_off, deg, elist, a_s, a_d, h_ws, bias, d_out, flags, N);
}